// Round 4
// baseline (231.789 us; speedup 1.0000x reference)
//
#include <hip/hip_runtime.h>
#include <hip/hip_bf16.h>

// Problem constants (fixed by setup_inputs)
#define NB 4
#define SEQ 2048
#define HID 768
#define NSPAN 16384            // spans per batch
#define M_TOT (NB * NSPAN)     // 65536 rows
#define K2 1536                // 2*HID
#define NTILE 24               // K2 / 64
#define CMP_CAP 66048          // compacted-table capacity (65536 + pad)

typedef float f32x4 __attribute__((ext_vector_type(4)));
typedef short s16x8 __attribute__((ext_vector_type(8)));
using bf16 = __hip_bfloat16;

// global -> LDS direct (16B per lane). LDS dest is wave-uniform base + lane*16;
// global src is per-lane (gather-capable).
__device__ __forceinline__ void gll16(const void* g, void* l) {
    __builtin_amdgcn_global_load_lds(
        (const __attribute__((address_space(1))) unsigned*)g,
        (__attribute__((address_space(3))) unsigned*)l, 16, 0, 0);
}

// ---------------------------------------------------------------------------
// Detect span_masks dtype: int32 words (0/1) vs byte-packed bools.
__global__ void mask_detect_kernel(const unsigned* __restrict__ masks, int* __restrict__ flag) {
    int t = blockIdx.x * 256 + threadIdx.x;
    if (t < 16384) {
        unsigned v = masks[t];
        if (v > 1u) atomicOr(flag, 1);   // multi-byte pattern => byte-packed bools
    }
}

__device__ __forceinline__ bool mask_at(const int* masks, int u8, int m) {
    return u8 ? (((const unsigned char*)masks)[m] != 0) : (masks[m] != 0);
}

// ---------------------------------------------------------------------------
// Default-fill compacted tables (pad rows: gather M3 row 0, no output store).
// Must run BEFORE scatter_kernel.
__global__ void init_compact_kernel(int* __restrict__ cS, int* __restrict__ cE,
                                    int* __restrict__ cO) {
    int i = blockIdx.x * 256 + threadIdx.x;
    if (i < CMP_CAP) { cS[i] = 0; cE[i] = 0; cO[i] = -1; }
}

// ---------------------------------------------------------------------------
// Order-preserving compaction, pass 1: per-256-span block active count.
__global__ void count_kernel(const int* __restrict__ masks, const int* __restrict__ flag,
                             int* __restrict__ blockCnt) {
    int bid = blockIdx.x, tid = threadIdx.x;
    bool act = mask_at(masks, flag[0], bid * 256 + tid);
    unsigned long long b = __ballot(act);
    __shared__ int wc[4];
    if ((tid & 63) == 0) wc[tid >> 6] = __popcll(b);
    __syncthreads();
    if (tid == 0) blockCnt[bid] = wc[0] + wc[1] + wc[2] + wc[3];
}

// Pass 2: exclusive scan over the 256 block counts (single block).
__global__ void scan_kernel(const int* __restrict__ blockCnt, int* __restrict__ blockOff,
                            int* __restrict__ cnt) {
    __shared__ int s[256];
    int t = threadIdx.x;
    int mine = blockCnt[t];
    s[t] = mine;
    __syncthreads();
    for (int d = 1; d < 256; d <<= 1) {
        int v = (t >= d) ? s[t - d] : 0;
        __syncthreads();
        s[t] += v;
        __syncthreads();
    }
    blockOff[t] = s[t] - mine;          // exclusive prefix
    if (t == 255) cnt[0] = s[255];
}

// Pass 3: rank-scatter (original m order preserved -> batch-slab locality).
__global__ void scatter_kernel(const int* __restrict__ span_ids, const int* __restrict__ masks,
                               const int* __restrict__ flag, const int* __restrict__ pooling,
                               const int* __restrict__ blockOff,
                               int* __restrict__ cS, int* __restrict__ cE, int* __restrict__ cO) {
    int bid = blockIdx.x, tid = threadIdx.x;
    int m = bid * 256 + tid;
    bool act = mask_at(masks, flag[0], m);
    unsigned long long b = __ballot(act);
    __shared__ int wbase[4];
    int lane = tid & 63, w = tid >> 6;
    if (lane == 0) wbase[w] = __popcll(b);
    __syncthreads();
    if (tid == 0) {
        int a = 0;
#pragma unroll
        for (int i = 0; i < 4; ++i) { int c = wbase[i]; wbase[i] = a; a += c; }
    }
    __syncthreads();
    if (act) {
        int rank = __popcll(b & ((1ULL << lane) - 1ULL));
        int idx = blockOff[bid] + wbase[w] + rank;
        int s = span_ids[2 * m], e = span_ids[2 * m + 1];
        int bb = m >> 14;                      // m / NSPAN
        int window = (pooling[0] != 0) ? 1 : 3;
        int cw = min(window, e - s);           // e-s >= 1 always
        int base = (bb * 3 + (cw - 1)) * SEQ;
        cS[idx] = base + s;
        cE[idx] = base + (e - cw);
        cO[idx] = m;
    }
}

// ---------------------------------------------------------------------------
// Masked-out rows: out[m] = bias. One wave per row, grid-stride.
__global__ void bias_fill_kernel(const int* __restrict__ masks, const int* __restrict__ flag,
                                 const float* __restrict__ bias, float* __restrict__ out) {
    int wave = (blockIdx.x * 256 + threadIdx.x) >> 6;   // 0..4095
    int lane = threadIdx.x & 63;
    int u8 = flag[0];
    for (int m = wave; m < M_TOT; m += 4096) {
        if (!mask_at(masks, u8, m)) {
            float* o = out + (size_t)m * HID;
#pragma unroll
            for (int c = 0; c < 3; ++c) {
                int h = (lane + c * 64) * 4;
                *(f32x4*)(o + h) = *(const f32x4*)(bias + h);
            }
        }
    }
}

// ---------------------------------------------------------------------------
// M3[b][c][p][h] = max over T[b, p .. p+c] (c = 0,1,2 => window 1,2,3), bf16.
__global__ void prep_m3_kernel(const float* __restrict__ T, bf16* __restrict__ M3) {
    int b = blockIdx.y;
    int p0 = blockIdx.x * 16;
    int t = threadIdx.x;   // 256
    const float* Tb = T + (size_t)b * SEQ * HID;
    bf16* o0 = M3 + (size_t)(b * 3 + 0) * SEQ * HID;
    bf16* o1 = M3 + (size_t)(b * 3 + 1) * SEQ * HID;
    bf16* o2 = M3 + (size_t)(b * 3 + 2) * SEQ * HID;
#pragma unroll
    for (int c = 0; c < 3; ++c) {
        int h = t + c * 256;
        float x0 = Tb[(size_t)p0 * HID + h];
        float x1 = Tb[(size_t)min(p0 + 1, SEQ - 1) * HID + h];
        for (int i = 0; i < 16; ++i) {
            int p = p0 + i;
            float x2 = Tb[(size_t)min(p + 2, SEQ - 1) * HID + h];
            float m2 = fmaxf(x0, x1);
            float m3v = fmaxf(m2, x2);
            size_t off = (size_t)p * HID + h;
            o0[off] = __float2bfloat16(x0);
            o1[off] = __float2bfloat16(m2);
            o2[off] = __float2bfloat16(m3v);
            x0 = x1; x1 = x2;
        }
    }
}

// ---------------------------------------------------------------------------
// Wt[n][k] = bf16(W[k][n]); W is (K2, HID) f32 row-major. 64x64 LDS transpose.
__global__ void prep_wt_kernel(const float* __restrict__ W, bf16* __restrict__ Wt) {
    __shared__ float tile[64][65];
    int k0 = blockIdx.x * 64;
    int n0 = blockIdx.y * 64;
    int t = threadIdx.x;
    int c = t & 63, r4 = t >> 6;
    for (int r = r4; r < 64; r += 4)
        tile[r][c] = W[(size_t)(k0 + r) * HID + n0 + c];
    __syncthreads();
    for (int r = r4; r < 64; r += 4)
        Wt[(size_t)(n0 + r) * K2 + k0 + c] = __float2bfloat16(tile[c][r]);
}

// ---------------------------------------------------------------------------
// GEMM over compacted rows with a counted-vmcnt double-buffered pipeline.
// Per tile t (24 tiles of BK=64):
//   s_waitcnt vmcnt(8)   [stage(t) landed; stage(t+1) may fly]
//   s_barrier            [all waves' stage(t) landed]
//   ds_read + 32 MFMA from buf[t&1]
//   s_barrier            [buf[t&1] fully consumed]
//   issue stage(t+2) -> buf[t&1]   [8 global_load_lds, 1KB each]
// Race-free: writes to buf[t&1] are issued only after all reads of tile t;
// next read of that buffer (tile t+2) is gated by its own vmcnt(8).
__global__ __launch_bounds__(256, 2)
void span_gemm_kernel(const bf16* __restrict__ M3, const bf16* __restrict__ Wt,
                      const int* __restrict__ cS, const int* __restrict__ cE,
                      const int* __restrict__ cO, const int* __restrict__ cnt,
                      const float* __restrict__ bias, float* __restrict__ out) {
    __shared__ char lds[65536];   // [0,32K): A buf0/buf1 ; [32K,64K): B buf0/buf1
    __shared__ int rS[128], rE[128], rO[128];

    const int tid = threadIdx.x;
    const int n0 = blockIdx.x * 128;   // 6 col tiles
    const int m0 = blockIdx.y * 128;   // 512 row tiles (early-exit past count)

    if (m0 >= cnt[0]) return;          // block-uniform early exit

    if (tid < 128) {
        int m = m0 + tid;
        rS[tid] = cS[m];
        rE[tid] = cE[m];
        rO[tid] = cO[m];
    }
    __syncthreads();

    const int lane = tid & 63, w = tid >> 6;
    const int wr = w >> 1, wc = w & 1;        // wave 2x2 over the 128x128 tile
    const int lr = lane & 15, lg = lane >> 4;

    // Staging geometry: per K-tile each operand is 128 rows x 128 B = 8 KB
    // = 8 wave-issues of 1KB; 4 issues per thread per operand.
    // 16B source chunk XOR-swizzled by row&7 (matched on the read side).
    const int lrow8 = lane >> 3;
    const int chunkp = ((lane & 7) ^ lrow8) << 4;

    const char* aS[4];
    const char* aE[4];
    const char* bP[4];
    int ldsOff[4];
#pragma unroll
    for (int it = 0; it < 4; ++it) {
        int i = it * 4 + w;                    // 1KB-issue index 0..31
        int r = i * 8 + lrow8;                 // LDS row 0..127
        aS[it] = (const char*)M3 + (size_t)rS[r] * (HID * 2) + chunkp;
        aE[it] = (const char*)M3 + (size_t)rE[r] * (HID * 2) + chunkp;
        bP[it] = (const char*)Wt + (size_t)(n0 + r) * (K2 * 2) + chunkp;
        ldsOff[it] = i * 1024;                 // wave-uniform dest
    }

#define STAGE(KT, CUR) do {                                               \
        const int _kt = (KT) * 64;                                        \
        const int _h = (_kt >= HID);                                      \
        const int _colB = (_kt - (_h ? HID : 0)) * 2;                     \
        const int _ktB = _kt * 2;                                         \
        char* _la = lds + (CUR) * 16384;                                  \
        char* _lb = lds + 32768 + (CUR) * 16384;                          \
        _Pragma("unroll")                                                 \
        for (int _it = 0; _it < 4; ++_it)                                 \
            gll16((_h ? aE[_it] : aS[_it]) + _colB, _la + ldsOff[_it]);   \
        _Pragma("unroll")                                                 \
        for (int _it = 0; _it < 4; ++_it)                                 \
            gll16(bP[_it] + _ktB, _lb + ldsOff[_it]);                     \
    } while (0)

    f32x4 acc[4][4];
#pragma unroll
    for (int i = 0; i < 4; i++)
#pragma unroll
        for (int j = 0; j < 4; j++) acc[i][j] = (f32x4){0.f, 0.f, 0.f, 0.f};

    // Prologue: stage tiles 0 and 1 (16 loads outstanding).
    STAGE(0, 0);
    STAGE(1, 1);

    for (int t = 0; t < NTILE; ++t) {
        const int cur = t & 1;
        if (t < NTILE - 1) {
            asm volatile("s_waitcnt vmcnt(8)" ::: "memory");
        } else {
            asm volatile("s_waitcnt vmcnt(0)" ::: "memory");
        }
        __builtin_amdgcn_sched_barrier(0);
        __builtin_amdgcn_s_barrier();
        __builtin_amdgcn_sched_barrier(0);

        const char* la = lds + cur * 16384;
        const char* lb = lds + 32768 + cur * 16384;
        __builtin_amdgcn_s_setprio(1);
#pragma unroll
        for (int kk = 0; kk < 2; ++kk) {
            const int cb = kk * 4 + lg;        // 16B-chunk index (k/8)
            s16x8 af[4], bfr[4];
#pragma unroll
            for (int i = 0; i < 4; ++i) {
                int row = wr * 64 + i * 16 + lr;
                af[i] = *(const s16x8*)(la + row * 128 + ((cb ^ (row & 7)) << 4));
            }
#pragma unroll
            for (int j = 0; j < 4; ++j) {
                int row = wc * 64 + j * 16 + lr;
                bfr[j] = *(const s16x8*)(lb + row * 128 + ((cb ^ (row & 7)) << 4));
            }
#pragma unroll
            for (int i = 0; i < 4; ++i)
#pragma unroll
                for (int j = 0; j < 4; ++j)
                    acc[i][j] = __builtin_amdgcn_mfma_f32_16x16x32_bf16(af[i], bfr[j], acc[i][j], 0, 0, 0);
        }
        __builtin_amdgcn_s_setprio(0);

        __builtin_amdgcn_sched_barrier(0);
        __builtin_amdgcn_s_barrier();
        __builtin_amdgcn_sched_barrier(0);

        if (t < NTILE - 2) STAGE(t + 2, cur);
    }
#undef STAGE

    // Epilogue: C/D layout (verified m89): col = lane&15, row = (lane>>4)*4 + q
#pragma unroll
    for (int i = 0; i < 4; i++) {
#pragma unroll
        for (int j = 0; j < 4; j++) {
#pragma unroll
            for (int q = 0; q < 4; q++) {
                int mloc = wr * 64 + i * 16 + lg * 4 + q;
                int o = rO[mloc];
                if (o >= 0) {
                    int n = n0 + wc * 64 + j * 16 + lr;
                    out[(size_t)o * HID + n] = acc[i][j][q] + bias[n];
                }
            }
        }
    }
}

// ---------------------------------------------------------------------------
extern "C" void kernel_launch(void* const* d_in, const int* in_sizes, int n_in,
                              void* d_out, int out_size, void* d_ws, size_t ws_size,
                              hipStream_t stream) {
    const float* token_reps = (const float*)d_in[0];
    const int*   span_ids   = (const int*)d_in[1];
    const int*   span_masks = (const int*)d_in[2];
    const int*   pooling    = (const int*)d_in[3];
    const float* W          = (const float*)d_in[4];
    const float* bias       = (const float*)d_in[5];
    float* out = (float*)d_out;

    // ws layout:
    //   [0,4) flag | [4,8) cnt | [1024,+1KB) blockCnt | [2048,+1KB) blockOff
    //   [4096, ..) cS / cE / cO (CMP_CAP ints each)
    //   [1MB, +37.75MB) M3 | then Wt (2.25MB)
    char* ws = (char*)d_ws;
    int*  flag = (int*)ws;
    int*  cnt  = (int*)(ws + 4);
    int*  blockCnt = (int*)(ws + 1024);
    int*  blockOff = (int*)(ws + 2048);
    int*  cS   = (int*)(ws + 4096);
    int*  cE   = (int*)(ws + 4096 + 4 * CMP_CAP);
    int*  cO   = (int*)(ws + 4096 + 8 * CMP_CAP);
    bf16* M3   = (bf16*)(ws + (1 << 20));
    const size_t M3_BYTES = (size_t)NB * 3 * SEQ * HID * 2;   // 37,748,736
    bf16* Wt   = (bf16*)(ws + (1 << 20) + M3_BYTES);

    hipMemsetAsync(ws, 0, 64, stream);
    mask_detect_kernel<<<64, 256, 0, stream>>>((const unsigned*)span_masks, flag);
    init_compact_kernel<<<(CMP_CAP + 255) / 256, 256, 0, stream>>>(cS, cE, cO);
    count_kernel<<<M_TOT / 256, 256, 0, stream>>>(span_masks, flag, blockCnt);
    scan_kernel<<<1, 256, 0, stream>>>(blockCnt, blockOff, cnt);
    scatter_kernel<<<M_TOT / 256, 256, 0, stream>>>(span_ids, span_masks, flag, pooling,
                                                    blockOff, cS, cE, cO);
    prep_m3_kernel<<<dim3(SEQ / 16, NB), 256, 0, stream>>>(token_reps, M3);
    prep_wt_kernel<<<dim3(K2 / 64, HID / 64), 256, 0, stream>>>(W, Wt);
    bias_fill_kernel<<<1024, 256, 0, stream>>>(span_masks, flag, bias, out);
    span_gemm_kernel<<<dim3(HID / 128, M_TOT / 128), 256, 0, stream>>>(
        M3, Wt, cS, cE, cO, cnt, bias, out);
}

// Round 5
// 193.713 us; speedup vs baseline: 1.1966x; 1.1966x over previous
//
#include <hip/hip_runtime.h>
#include <hip/hip_bf16.h>

// Problem constants (fixed by setup_inputs)
#define NB 4
#define SEQ 2048
#define HID 768
#define NSPAN 16384            // spans per batch
#define M_TOT (NB * NSPAN)     // 65536 rows
#define K2 1536                // 2*HID
#define CMP_CAP 66048          // compacted-table capacity = 516*128
#define MTILES 516             // grid.y: covers active GEMM tiles + inactive fill

typedef float f32x4 __attribute__((ext_vector_type(4)));
typedef short s16x8 __attribute__((ext_vector_type(8)));
using bf16 = __hip_bfloat16;

// global -> LDS direct (16B per lane). LDS dest is wave-uniform base + lane*16;
// global src is per-lane (gather-capable).
__device__ __forceinline__ void gll16(const void* g, void* l) {
    __builtin_amdgcn_global_load_lds(
        (const __attribute__((address_space(1))) unsigned*)g,
        (__attribute__((address_space(3))) unsigned*)l, 16, 0, 0);
}

// ---------------------------------------------------------------------------
// Detect span_masks dtype: int32 words (0/1) vs byte-packed bools.
__global__ void mask_detect_kernel(const unsigned* __restrict__ masks, int* __restrict__ flag) {
    int t = blockIdx.x * 256 + threadIdx.x;
    if (t < 16384) {
        unsigned v = masks[t];
        if (v > 1u) atomicOr(flag, 1);   // multi-byte pattern => byte-packed bools
    }
}

__device__ __forceinline__ bool mask_at(const int* masks, int u8, int m) {
    return u8 ? (((const unsigned char*)masks)[m] != 0) : (masks[m] != 0);
}

// ---------------------------------------------------------------------------
// Default-fill compacted tables (pad rows: gather M3 row 0, no output store).
__global__ void init_compact_kernel(int* __restrict__ cS, int* __restrict__ cE,
                                    int* __restrict__ cO) {
    int i = blockIdx.x * 256 + threadIdx.x;
    if (i < CMP_CAP) { cS[i] = 0; cE[i] = 0; cO[i] = -1; }
}

// ---------------------------------------------------------------------------
// Order-preserving compaction, pass 1: per-256-span block active count.
__global__ void count_kernel(const int* __restrict__ masks, const int* __restrict__ flag,
                             int* __restrict__ blockCnt) {
    int bid = blockIdx.x, tid = threadIdx.x;
    bool act = mask_at(masks, flag[0], bid * 256 + tid);
    unsigned long long b = __ballot(act);
    __shared__ int wc[4];
    if ((tid & 63) == 0) wc[tid >> 6] = __popcll(b);
    __syncthreads();
    if (tid == 0) blockCnt[bid] = wc[0] + wc[1] + wc[2] + wc[3];
}

// Pass 2: exclusive scan over the 256 block counts (single block).
__global__ void scan_kernel(const int* __restrict__ blockCnt, int* __restrict__ blockOff,
                            int* __restrict__ cnt) {
    __shared__ int s[256];
    int t = threadIdx.x;
    int mine = blockCnt[t];
    s[t] = mine;
    __syncthreads();
    for (int d = 1; d < 256; d <<= 1) {
        int v = (t >= d) ? s[t - d] : 0;
        __syncthreads();
        s[t] += v;
        __syncthreads();
    }
    blockOff[t] = s[t] - mine;          // exclusive prefix
    if (t == 255) cnt[0] = s[255];
}

// Pass 3: rank-scatter, order-preserving for BOTH active (cS/cE/cO) and
// inactive (cI) rows. Preserved order => batch-slab L2/L3 locality in GEMM.
__global__ void scatter_kernel(const int* __restrict__ span_ids, const int* __restrict__ masks,
                               const int* __restrict__ flag, const int* __restrict__ pooling,
                               const int* __restrict__ blockOff,
                               int* __restrict__ cS, int* __restrict__ cE,
                               int* __restrict__ cO, int* __restrict__ cI) {
    int bid = blockIdx.x, tid = threadIdx.x;
    int m = bid * 256 + tid;
    bool act = mask_at(masks, flag[0], m);
    unsigned long long b = __ballot(act);
    __shared__ int wA[4], wI[4];
    int lane = tid & 63, w = tid >> 6;
    int wAct = __popcll(b);
    if (lane == 0) { wA[w] = wAct; wI[w] = 64 - wAct; }
    __syncthreads();
    if (tid == 0) {
        int a = 0, ii = 0;
#pragma unroll
        for (int i = 0; i < 4; ++i) {
            int ca = wA[i], ci = wI[i];
            wA[i] = a; wI[i] = ii; a += ca; ii += ci;
        }
    }
    __syncthreads();
    unsigned long long below = (lane == 63) ? ~0ULL >> 1 : ((1ULL << lane) - 1ULL);
    if (act) {
        int rank = __popcll(b & below);
        int idx = blockOff[bid] + wA[w] + rank;
        int s = span_ids[2 * m], e = span_ids[2 * m + 1];
        int bb = m >> 14;                      // m / NSPAN
        int window = (pooling[0] != 0) ? 1 : 3;
        int cw = min(window, e - s);           // e-s >= 1 always
        int base = (bb * 3 + (cw - 1)) * SEQ;
        cS[idx] = base + s;
        cE[idx] = base + (e - cw);
        cO[idx] = m;
    } else {
        int rank = __popcll(~b & below);
        int idx = (bid * 256 - blockOff[bid]) + wI[w] + rank;
        cI[idx] = m;
    }
}

// ---------------------------------------------------------------------------
// M3[b][c][p][h] = max over T[b, p .. p+c] (c = 0,1,2 => window 1,2,3), bf16.
__global__ void prep_m3_kernel(const float* __restrict__ T, bf16* __restrict__ M3) {
    int b = blockIdx.y;
    int p0 = blockIdx.x * 16;
    int t = threadIdx.x;   // 256
    const float* Tb = T + (size_t)b * SEQ * HID;
    bf16* o0 = M3 + (size_t)(b * 3 + 0) * SEQ * HID;
    bf16* o1 = M3 + (size_t)(b * 3 + 1) * SEQ * HID;
    bf16* o2 = M3 + (size_t)(b * 3 + 2) * SEQ * HID;
#pragma unroll
    for (int c = 0; c < 3; ++c) {
        int h = t + c * 256;
        float x0 = Tb[(size_t)p0 * HID + h];
        float x1 = Tb[(size_t)min(p0 + 1, SEQ - 1) * HID + h];
        for (int i = 0; i < 16; ++i) {
            int p = p0 + i;
            float x2 = Tb[(size_t)min(p + 2, SEQ - 1) * HID + h];
            float m2 = fmaxf(x0, x1);
            float m3v = fmaxf(m2, x2);
            size_t off = (size_t)p * HID + h;
            o0[off] = __float2bfloat16(x0);
            o1[off] = __float2bfloat16(m2);
            o2[off] = __float2bfloat16(m3v);
            x0 = x1; x1 = x2;
        }
    }
}

// ---------------------------------------------------------------------------
// Wt[n][k] = bf16(W[k][n]); W is (K2, HID) f32 row-major. 64x64 LDS transpose.
__global__ void prep_wt_kernel(const float* __restrict__ W, bf16* __restrict__ Wt) {
    __shared__ float tile[64][65];
    int k0 = blockIdx.x * 64;
    int n0 = blockIdx.y * 64;
    int t = threadIdx.x;
    int c = t & 63, r4 = t >> 6;
    for (int r = r4; r < 64; r += 4)
        tile[r][c] = W[(size_t)(k0 + r) * HID + n0 + c];
    __syncthreads();
    for (int r = r4; r < 64; r += 4)
        Wt[(size_t)(n0 + r) * K2 + k0 + c] = __float2bfloat16(tile[c][r]);
}

// ---------------------------------------------------------------------------
// GEMM over compacted ACTIVE rows (R2's proven single-buffer structure:
// 32KB LDS, 4 blocks/CU, compiler-drained __syncthreads). Blocks whose m-tile
// is past the active count instead fill bias into INACTIVE rows (cI table).
// A[m] = [ M3row(cS[m]) | M3row(cE[m]) ], gathered via per-lane
// global_load_lds sources; 16B-chunk XOR swizzle on source AND read (rule 21).
__global__ __launch_bounds__(256, 2)
void span_gemm_kernel(const bf16* __restrict__ M3, const bf16* __restrict__ Wt,
                      const int* __restrict__ cS, const int* __restrict__ cE,
                      const int* __restrict__ cO, const int* __restrict__ cI,
                      const int* __restrict__ cnt,
                      const float* __restrict__ bias, float* __restrict__ out) {
    __shared__ char lA[128 * 128];   // 16 KB
    __shared__ char lB[128 * 128];   // 16 KB
    __shared__ int rS[128], rE[128], rO[128];

    const int tid = threadIdx.x;
    const int n0 = blockIdx.x * 128;   // 6 col tiles
    const int count = cnt[0];
    const int actTiles = (count + 127) >> 7;

    if ((int)blockIdx.y >= actTiles) {
        // ---- inactive fill: out[cI[r]][n0..n0+128) = bias[n0..n0+128) ----
        int r = (blockIdx.y - actTiles) * 128 + (tid >> 1);
        if (r < M_TOT - count) {
            int o = cI[r];
            const float* bsrc = bias + n0 + (tid & 1) * 64;
            float* dst = out + (size_t)o * HID + n0 + (tid & 1) * 64;
#pragma unroll
            for (int c = 0; c < 16; ++c)
                *(f32x4*)(dst + c * 4) = *(const f32x4*)(bsrc + c * 4);
        }
        return;
    }

    const int m0 = blockIdx.y * 128;

    if (tid < 128) {
        int m = m0 + tid;
        rS[tid] = cS[m];
        rE[tid] = cE[m];
        rO[tid] = cO[m];
    }
    __syncthreads();

    const int lane = tid & 63, w = tid >> 6;
    const int wr = w >> 1, wc = w & 1;        // wave 2x2 over the 128x128 tile
    const int lr = lane & 15, lg = lane >> 4;

    // Staging geometry: per K-step each operand is 128 rows x 128 B = 8KB
    // = 8 wave-issues of 1KB; 4 issues per thread per operand.
    const int lrow8 = lane >> 3;
    const int chunkp = ((lane & 7) ^ lrow8) << 4;   // swizzled byte offset in row

    const char* aPtr[2][4];
    const char* bPtr[4];
    int ldsOff[4];
#pragma unroll
    for (int it = 0; it < 4; ++it) {
        int i = it * 4 + w;                    // 1KB-issue index 0..31
        int r = i * 8 + lrow8;                 // LDS row 0..127
        aPtr[0][it] = (const char*)M3 + (size_t)rS[r] * (HID * 2) + chunkp;
        aPtr[1][it] = (const char*)M3 + (size_t)rE[r] * (HID * 2) + chunkp;
        bPtr[it]    = (const char*)Wt + (size_t)(n0 + r) * (K2 * 2) + chunkp;
        ldsOff[it]  = i * 1024;                // wave-uniform dest
    }

    f32x4 acc[4][4];
#pragma unroll
    for (int i = 0; i < 4; i++)
#pragma unroll
        for (int j = 0; j < 4; j++) acc[i][j] = (f32x4){0.f, 0.f, 0.f, 0.f};

    for (int kt = 0; kt < K2; kt += 64) {
        const int half = (kt >= HID) ? 1 : 0;
        const int colB = (kt - (half ? HID : 0)) * 2;   // byte col within M3 row
        const int ktB  = kt * 2;                        // byte col within Wt row
        __syncthreads();   // previous tile fully consumed by all waves
#pragma unroll
        for (int it = 0; it < 4; ++it)
            gll16(aPtr[half][it] + colB, lA + ldsOff[it]);
#pragma unroll
        for (int it = 0; it < 4; ++it)
            gll16(bPtr[it] + ktB, lB + ldsOff[it]);
        __syncthreads();   // vmcnt(0) drained by compiler before barrier
#pragma unroll
        for (int kk = 0; kk < 2; ++kk) {
            const int cb = kk * 4 + lg;        // global 16B-chunk index (k/8)
            s16x8 af[4], bfr[4];
#pragma unroll
            for (int i = 0; i < 4; ++i) {
                int row = wr * 64 + i * 16 + lr;
                af[i] = *(const s16x8*)(lA + row * 128 + ((cb ^ (row & 7)) << 4));
            }
#pragma unroll
            for (int j = 0; j < 4; ++j) {
                int row = wc * 64 + j * 16 + lr;
                bfr[j] = *(const s16x8*)(lB + row * 128 + ((cb ^ (row & 7)) << 4));
            }
#pragma unroll
            for (int i = 0; i < 4; ++i)
#pragma unroll
                for (int j = 0; j < 4; ++j)
                    acc[i][j] = __builtin_amdgcn_mfma_f32_16x16x32_bf16(af[i], bfr[j], acc[i][j], 0, 0, 0);
        }
    }

    // Epilogue: C/D layout (verified m89): col = lane&15, row = (lane>>4)*4 + q
#pragma unroll
    for (int i = 0; i < 4; i++) {
#pragma unroll
        for (int j = 0; j < 4; j++) {
#pragma unroll
            for (int q = 0; q < 4; q++) {
                int mloc = wr * 64 + i * 16 + lg * 4 + q;
                int o = rO[mloc];
                if (o >= 0) {
                    int n = n0 + wc * 64 + j * 16 + lr;
                    out[(size_t)o * HID + n] = acc[i][j][q] + bias[n];
                }
            }
        }
    }
}

// ---------------------------------------------------------------------------
extern "C" void kernel_launch(void* const* d_in, const int* in_sizes, int n_in,
                              void* d_out, int out_size, void* d_ws, size_t ws_size,
                              hipStream_t stream) {
    const float* token_reps = (const float*)d_in[0];
    const int*   span_ids   = (const int*)d_in[1];
    const int*   span_masks = (const int*)d_in[2];
    const int*   pooling    = (const int*)d_in[3];
    const float* W          = (const float*)d_in[4];
    const float* bias       = (const float*)d_in[5];
    float* out = (float*)d_out;

    // ws layout:
    //   [0,4) flag | [4,8) cnt | [1024,+1KB) blockCnt | [2048,+1KB) blockOff
    //   [4096) cS | cE | cO (CMP_CAP ints each) | cI (M_TOT ints)
    //   [2MB, +37.75MB) M3 | then Wt (2.25MB)
    char* ws = (char*)d_ws;
    int*  flag = (int*)ws;
    int*  cnt  = (int*)(ws + 4);
    int*  blockCnt = (int*)(ws + 1024);
    int*  blockOff = (int*)(ws + 2048);
    int*  cS   = (int*)(ws + 4096);
    int*  cE   = (int*)(ws + 4096 + 4 * CMP_CAP);
    int*  cO   = (int*)(ws + 4096 + 8 * CMP_CAP);
    int*  cI   = (int*)(ws + 4096 + 12 * CMP_CAP);
    bf16* M3   = (bf16*)(ws + (2 << 20));
    const size_t M3_BYTES = (size_t)NB * 3 * SEQ * HID * 2;   // 37,748,736
    bf16* Wt   = (bf16*)(ws + (2 << 20) + M3_BYTES);

    hipMemsetAsync(ws, 0, 64, stream);
    mask_detect_kernel<<<64, 256, 0, stream>>>((const unsigned*)span_masks, flag);
    init_compact_kernel<<<(CMP_CAP + 255) / 256, 256, 0, stream>>>(cS, cE, cO);
    count_kernel<<<M_TOT / 256, 256, 0, stream>>>(span_masks, flag, blockCnt);
    scan_kernel<<<1, 256, 0, stream>>>(blockCnt, blockOff, cnt);
    scatter_kernel<<<M_TOT / 256, 256, 0, stream>>>(span_ids, span_masks, flag, pooling,
                                                    blockOff, cS, cE, cO, cI);
    prep_m3_kernel<<<dim3(SEQ / 16, NB), 256, 0, stream>>>(token_reps, M3);
    prep_wt_kernel<<<dim3(K2 / 64, HID / 64), 256, 0, stream>>>(W, Wt);
    span_gemm_kernel<<<dim3(HID / 128, MTILES), 256, 0, stream>>>(
        M3, Wt, cS, cE, cO, cI, cnt, bias, out);
}